// Round 10
// baseline (274.170 us; speedup 1.0000x reference)
//
#include <hip/hip_runtime.h>
#include <hip/hip_fp16.h>

// ImplicitPointHead fused (MI355X / gfx950) — round 10
// r9: waves_per_eu no-op (VGPR stuck 60); register-pipeline lever dead.
// Remaining axis: TLP. PT 64->32: LDS 70.7->35.3KB -> 4 blocks/CU = 32
// waves/CU (HW max, 8/SIMD, was 4/SIMD). Wave keeps 1x8 grid (32ch x all pts,
// B-reads at per-block minimum). Cost: B L2-traffic x2 (~28 TB/s aggregate,
// 81% of ceiling) - the doubled TLP is what hides those latencies.
// launch_bounds(512,8) pins VGPR<=64 for 8 waves/EU.

#define NI      128
#define NPTS    2048
#define CH      256
#define NPARAM  263169
#define PT      32
#define NTILES  (NPTS / PT)     // 64
#define ROWS    536             // 67x16B per row (odd -> minimal b128 aliasing)

#define WOFF0   0
#define WOFF1   131072
#define WOFF2   196608
#define WOFF3   262144
#define BOFF0   262400
#define BOFF1   262656
#define BOFF2   262912
#define BOFF3   263168

// fragment-layout f16 weight cache in d_ws (per instance, f16 offsets)
#define PI_L0   0        // 16 ks * 16 cb * 64 lane * 8
#define PI_L1   131072
#define PI_L2   196608
#define PI_L3   262144
#define WS_PER_INST 262400
#define WS_BYTES ((size_t)NI * WS_PER_INST * 2)

typedef __fp16   h16x2 __attribute__((ext_vector_type(2)));
typedef _Float16 f16x8 __attribute__((ext_vector_type(8)));
typedef float    f32x4 __attribute__((ext_vector_type(4)));

union pack8 { h16x2 h[4]; f16x8 v; };

// ---------------- prep: params fp32 -> fragment-ordered fp16 ----------------
// Frag cb, lane l covers ch co = (cb>>1)*32 + 2*(l&15) + (cb&1); k = ks*32+(l>>4)*8.
// (unchanged from r6 — layout is PT-independent)
__global__ __launch_bounds__(256) void iph_prep(
    const float* __restrict__ params, _Float16* __restrict__ wsw)
{
    const int inst = blockIdx.y;
    const int r = blockIdx.x * 256 + threadIdx.x;
    if (r >= 32800) return;
    const float* __restrict__ P = params + (size_t)inst * NPARAM;
    _Float16* __restrict__ W = wsw + (size_t)inst * WS_PER_INST;

    int rl, woff, K, dst;
    if (r < 16384)      { rl = r;         woff = WOFF0; K = 512; dst = PI_L0; }
    else if (r < 24576) { rl = r - 16384; woff = WOFF1; K = 256; dst = PI_L1; }
    else if (r < 32768) { rl = r - 24576; woff = WOFF2; K = 256; dst = PI_L2; }
    else {
        const int e = (r - 32768) * 8;
        f16x8 v;
        #pragma unroll
        for (int j = 0; j < 8; ++j) v[j] = (_Float16)P[WOFF3 + e + j];
        *(f16x8*)&W[PI_L3 + e] = v;
        return;
    }
    const int e    = rl * 8;
    const int lane = rl & 63;
    const int cb   = (rl >> 6) & 15;
    const int ks   = rl >> 10;
    const int co   = (cb >> 1) * 32 + 2 * (lane & 15) + (cb & 1);
    const int k    = ks * 32 + (lane >> 4) * 8;
    const float* __restrict__ src = P + woff + co * K + k;
    f16x8 v;
    #pragma unroll
    for (int j = 0; j < 8; ++j) v[j] = (_Float16)src[j];
    *(f16x8*)&W[dst + e] = v;
}

// ---------------- GEMM tile: 32 pts x 32 ch per wave ----------------
template<int NKS, bool PREPPED>
__device__ __forceinline__ void gemm_tile(
    f32x4 (&acc)[2][2],
    const _Float16* __restrict__ bsrc,   // WI + PI_Lx (fragment order)
    const float* __restrict__ pw,        // P + WOFFx (fallback)
    const _Float16* __restrict__ X,
    int lane, int wave, int l15, int hi)
{
    if constexpr (PREPPED) {
        const _Float16* bp = bsrc + ((wave * 2) * 64 + lane) * 8;
        const _Float16* ap = &X[l15 * ROWS + hi * 8];
        #pragma unroll
        for (int ks = 0; ks < NKS; ++ks) {
            f16x8 b0 = *(const f16x8*)(bp + ks * 8192);
            f16x8 b1 = *(const f16x8*)(bp + ks * 8192 + 512);
            f16x8 a0 = *(const f16x8*)(ap + ks * 32);
            f16x8 a1 = *(const f16x8*)(ap + 16 * ROWS + ks * 32);
            __builtin_amdgcn_s_setprio(1);
            acc[0][0] = __builtin_amdgcn_mfma_f32_16x16x32_f16(a0, b0, acc[0][0], 0, 0, 0);
            acc[0][1] = __builtin_amdgcn_mfma_f32_16x16x32_f16(a0, b1, acc[0][1], 0, 0, 0);
            acc[1][0] = __builtin_amdgcn_mfma_f32_16x16x32_f16(a1, b0, acc[1][0], 0, 0, 0);
            acc[1][1] = __builtin_amdgcn_mfma_f32_16x16x32_f16(a1, b1, acc[1][1], 0, 0, 0);
            __builtin_amdgcn_s_setprio(0);
        }
    } else {
        const int K = NKS * 32;
        for (int ks = 0; ks < NKS; ++ks) {
            f16x8 bfrag[2];
            #pragma unroll
            for (int nt = 0; nt < 2; ++nt) {
                const int co = wave * 32 + 2 * l15 + nt;
                const float* wp = pw + (size_t)co * K + ks * 32 + hi * 8;
                float w8[8];
                __builtin_memcpy(w8, wp, 32);
                f16x8 bb;
                #pragma unroll
                for (int j = 0; j < 8; ++j) bb[j] = (_Float16)w8[j];
                bfrag[nt] = bb;
            }
            f16x8 afrag[2];
            #pragma unroll
            for (int mt = 0; mt < 2; ++mt)
                afrag[mt] = *(const f16x8*)&X[(mt * 16 + l15) * ROWS + ks * 32 + hi * 8];
            #pragma unroll
            for (int mt = 0; mt < 2; ++mt)
                #pragma unroll
                for (int nt = 0; nt < 2; ++nt)
                    acc[mt][nt] = __builtin_amdgcn_mfma_f32_16x16x32_f16(
                        afrag[mt], bfrag[nt], acc[mt][nt], 0, 0, 0);
        }
    }
}

// ---------------- main fused kernel ----------------
template<bool PREPPED>
__global__ __launch_bounds__(512, 8) void iph_main(
    const float* __restrict__ feat,     // [128][256][2048]
    const float* __restrict__ coords,   // [128][2048][2]
    const float* __restrict__ params,   // [128][263169]
    const _Float16* __restrict__ wsw,   // fragment-ordered f16 weights
    const float* __restrict__ peg,      // [2][128]
    float* __restrict__ out)            // [128][1][2048]
{
    __shared__ _Float16 X[PT * ROWS];   // 34304 B
    __shared__ float    partial[8][PT]; // 1 KB -> 35.3 KB total, 4 blocks/CU

    const int bid  = blockIdx.x;        // 8192 blocks
    const int inst = (bid & 7) | ((bid >> 9) << 3);   // inst's 64 tiles on one XCD
    const int tile = (bid >> 3) & 63;
    const int p0   = tile * PT;
    const int tid  = threadIdx.x;
    const int lane = tid & 63;
    const int wave = tid >> 6;
    const int l15  = lane & 15;
    const int hi   = lane >> 4;
    const float* __restrict__ P = params + (size_t)inst * NPARAM;
    const _Float16* __restrict__ WI = wsw + (size_t)inst * WS_PER_INST;

    // ---- positional encoding -> X[pt][0..255]; 16 threads/pt, 8 freqs each
    {
        const int pt   = tid >> 4;     // 0..31
        const int part = tid & 15;     // 8 freqs each
        const float2 cc = *(const float2*)&coords[((size_t)inst * NPTS + p0 + pt) * 2];
        const float a = 2.f * cc.x - 1.f;
        const float b = 2.f * cc.y - 1.f;
        float sv[8], cv[8];
        #pragma unroll
        for (int j = 0; j < 8; ++j) {
            const int f = part * 8 + j;
            float locr = a * peg[f] + b * peg[128 + f];
            locr -= floorf(locr);                        // period-1 reduction
            sv[j] = __builtin_amdgcn_sinf(locr);         // sin(2*pi*x)
            cv[j] = __builtin_amdgcn_cosf(locr);
        }
        pack8 s0, c0;
        #pragma unroll
        for (int q = 0; q < 4; ++q) {
            s0.h[q] = __builtin_amdgcn_cvt_pkrtz(sv[2*q], sv[2*q + 1]);
            c0.h[q] = __builtin_amdgcn_cvt_pkrtz(cv[2*q], cv[2*q + 1]);
        }
        _Float16* base = &X[pt * ROWS + part * 8];
        *(f16x8*)(base)       = s0.v;
        *(f16x8*)(base + 128) = c0.v;
    }
    // ---- features -> X[pt][256..511]; thread: pt = tid&31, 16 ch chunk
    {
        const int p  = tid & 31;
        const int cg = tid >> 5;       // 0..15 -> channels cg*16..cg*16+15
        const float* fbase = feat + (size_t)inst * CH * NPTS + (size_t)(cg * 16) * NPTS + p0 + p;
        float w8[16];
        #pragma unroll
        for (int j = 0; j < 16; ++j)
            w8[j] = fbase[(size_t)j * NPTS];
        pack8 pk0, pk1;
        #pragma unroll
        for (int q = 0; q < 4; ++q) {
            pk0.h[q] = __builtin_amdgcn_cvt_pkrtz(w8[2*q],     w8[2*q + 1]);
            pk1.h[q] = __builtin_amdgcn_cvt_pkrtz(w8[8 + 2*q], w8[9 + 2*q]);
        }
        *(f16x8*)&X[p * ROWS + 256 + cg * 16]     = pk0.v;
        *(f16x8*)&X[p * ROWS + 256 + cg * 16 + 8] = pk1.v;
    }
    __syncthreads();

    // hidden-layer epilogue: relu(acc+b) -> X (even/odd half2 writes)
    auto write_epilogue = [&](f32x4 (&acc)[2][2], const float2 bb) {
        #pragma unroll
        for (int mt = 0; mt < 2; ++mt) {
            #pragma unroll
            for (int r = 0; r < 4; ++r) {
                // C/D layout (m89): col=lane&15, row=(lane>>4)*4+r
                const float v0 = fmaxf(acc[mt][0][r] + bb.x, 0.f);
                const float v1 = fmaxf(acc[mt][1][r] + bb.y, 0.f);
                const h16x2 e = __builtin_amdgcn_cvt_pkrtz(v0, v1);
                const int pt = mt * 16 + hi * 4 + r;
                *(h16x2*)&X[pt * ROWS + wave * 32 + 2 * l15] = e;
            }
        }
    };

    // ---- L0
    {
        f32x4 acc[2][2];
        #pragma unroll
        for (int mt = 0; mt < 2; ++mt)
            #pragma unroll
            for (int nt = 0; nt < 2; ++nt)
                acc[mt][nt] = (f32x4){0.f, 0.f, 0.f, 0.f};
        const float2 bb = *(const float2*)&P[BOFF0 + wave * 32 + 2 * l15];
        gemm_tile<16, PREPPED>(acc, WI + PI_L0, P + WOFF0, X, lane, wave, l15, hi);
        __syncthreads();
        write_epilogue(acc, bb);
        __syncthreads();
    }
    // ---- L1
    {
        f32x4 acc[2][2];
        #pragma unroll
        for (int mt = 0; mt < 2; ++mt)
            #pragma unroll
            for (int nt = 0; nt < 2; ++nt)
                acc[mt][nt] = (f32x4){0.f, 0.f, 0.f, 0.f};
        const float2 bb = *(const float2*)&P[BOFF1 + wave * 32 + 2 * l15];
        gemm_tile<8, PREPPED>(acc, WI + PI_L1, P + WOFF1, X, lane, wave, l15, hi);
        __syncthreads();
        write_epilogue(acc, bb);
        __syncthreads();
    }
    // ---- L2 + L3 fused: partial[wave][pt] = sum_{ch in wave} w3[ch]*relu(acc+b2)
    {
        f32x4 acc[2][2];
        #pragma unroll
        for (int mt = 0; mt < 2; ++mt)
            #pragma unroll
            for (int nt = 0; nt < 2; ++nt)
                acc[mt][nt] = (f32x4){0.f, 0.f, 0.f, 0.f};
        const float2 bb = *(const float2*)&P[BOFF2 + wave * 32 + 2 * l15];
        const float2 w3 = *(const float2*)&P[WOFF3 + wave * 32 + 2 * l15];
        gemm_tile<8, PREPPED>(acc, WI + PI_L2, P + WOFF2, X, lane, wave, l15, hi);
        #pragma unroll
        for (int mt = 0; mt < 2; ++mt) {
            #pragma unroll
            for (int r = 0; r < 4; ++r) {
                const float v0 = fmaxf(acc[mt][0][r] + bb.x, 0.f);
                const float v1 = fmaxf(acc[mt][1][r] + bb.y, 0.f);
                float s = v0 * w3.x + v1 * w3.y;
                s += __shfl_xor(s, 1);
                s += __shfl_xor(s, 2);
                s += __shfl_xor(s, 4);
                s += __shfl_xor(s, 8);
                if (l15 == 0)
                    partial[wave][mt * 16 + hi * 4 + r] = s;
            }
        }
        __syncthreads();
        if (tid < PT) {
            float s = P[BOFF3];
            #pragma unroll
            for (int w = 0; w < 8; ++w) s += partial[w][tid];
            out[(size_t)inst * NPTS + p0 + tid] = s;
        }
    }
}

extern "C" void kernel_launch(void* const* d_in, const int* in_sizes, int n_in,
                              void* d_out, int out_size, void* d_ws, size_t ws_size,
                              hipStream_t stream) {
    (void)in_sizes; (void)n_in; (void)out_size;
    const float* feat   = (const float*)d_in[0];
    const float* coords = (const float*)d_in[1];
    const float* params = (const float*)d_in[2];
    const float* peg    = (const float*)d_in[3];
    float* out = (float*)d_out;

    dim3 grid(NI * NTILES);   // 8192 blocks
    dim3 block(512);

    if (ws_size >= WS_BYTES) {
        _Float16* wsw = (_Float16*)d_ws;
        iph_prep<<<dim3(129, 128), dim3(256), 0, stream>>>(params, wsw);
        iph_main<true><<<grid, block, 0, stream>>>(feat, coords, params, wsw, peg, out);
    } else {
        iph_main<false><<<grid, block, 0, stream>>>(feat, coords, params,
                                                    (const _Float16*)d_ws, peg, out);
    }
}

// Round 11
// 215.264 us; speedup vs baseline: 1.2736x; 1.2736x over previous
//
#include <hip/hip_runtime.h>
#include <hip/hip_fp16.h>

// ImplicitPointHead fused (MI355X / gfx950) — round 11
// r10: occupancy 86% but WORSE -> perf tracks MFMA-per-exposed-B-latency; TLP
// axis dead. r5/6/9: compiler never builds reg prefetch (VGPR stuck ~60).
// This round: inline-asm B pipeline (T4 counted vmcnt, the HK mechanism):
//  - B-loads = asm volatile global_load_dwordx4, 5-slot queue, 4 ks deep
//  - explicit s_waitcnt vmcnt(8/6/4/2/0) + sched_barrier(0)  (rule #18)
//  - raw s_barrier with manual lgkmcnt discipline (no vmcnt drain!) so each
//    layer's B-prologue flies across phase boundaries; L0's issues at top,
//    hidden under PE+staging.

#define NI      128
#define NPTS    2048
#define CH      256
#define NPARAM  263169
#define PT      64
#define NTILES  (NPTS / PT)     // 32
#define ROWS    536             // 67x16B per row (odd -> minimal b128 aliasing)

#define WOFF0   0
#define WOFF1   131072
#define WOFF2   196608
#define WOFF3   262144
#define BOFF0   262400
#define BOFF1   262656
#define BOFF2   262912
#define BOFF3   263168

#define PI_L0   0        // 16 ks * 16 cb * 64 lane * 8
#define PI_L1   131072
#define PI_L2   196608
#define PI_L3   262144
#define WS_PER_INST 262400
#define WS_BYTES ((size_t)NI * WS_PER_INST * 2)

typedef __fp16   h16x2 __attribute__((ext_vector_type(2)));
typedef _Float16 f16x8 __attribute__((ext_vector_type(8)));
typedef float    f32x4 __attribute__((ext_vector_type(4)));

union pack8 { h16x2 h[4]; f16x8 v; };

// ---------------- prep: params fp32 -> fragment-ordered fp16 (r6) ----------------
__global__ __launch_bounds__(256) void iph_prep(
    const float* __restrict__ params, _Float16* __restrict__ wsw)
{
    const int inst = blockIdx.y;
    const int r = blockIdx.x * 256 + threadIdx.x;
    if (r >= 32800) return;
    const float* __restrict__ P = params + (size_t)inst * NPARAM;
    _Float16* __restrict__ W = wsw + (size_t)inst * WS_PER_INST;

    int rl, woff, K, dst;
    if (r < 16384)      { rl = r;         woff = WOFF0; K = 512; dst = PI_L0; }
    else if (r < 24576) { rl = r - 16384; woff = WOFF1; K = 256; dst = PI_L1; }
    else if (r < 32768) { rl = r - 24576; woff = WOFF2; K = 256; dst = PI_L2; }
    else {
        const int e = (r - 32768) * 8;
        f16x8 v;
        #pragma unroll
        for (int j = 0; j < 8; ++j) v[j] = (_Float16)P[WOFF3 + e + j];
        *(f16x8*)&W[PI_L3 + e] = v;
        return;
    }
    const int e    = rl * 8;
    const int lane = rl & 63;
    const int cb   = (rl >> 6) & 15;
    const int ks   = rl >> 10;
    const int co   = (cb >> 1) * 32 + 2 * (lane & 15) + (cb & 1);
    const int k    = ks * 32 + (lane >> 4) * 8;
    const float* __restrict__ src = P + woff + co * K + k;
    f16x8 v;
    #pragma unroll
    for (int j = 0; j < 8; ++j) v[j] = (_Float16)src[j];
    *(f16x8*)&W[dst + e] = v;
}

// ---------------- asm pipeline primitives ----------------
__device__ __forceinline__ void issue_b2(const _Float16* p, f16x8& r0, f16x8& r1) {
    const unsigned long long a = (unsigned long long)p;
    asm volatile("global_load_dwordx4 %0, %2, off\n\t"
                 "global_load_dwordx4 %1, %2, off offset:1024"
                 : "=&v"(r0), "=&v"(r1)
                 : "v"(a));
}

template<int N>
__device__ __forceinline__ void wait_vm() {
    if constexpr (N >= 8)      asm volatile("s_waitcnt vmcnt(8)" ::: "memory");
    else if constexpr (N == 6) asm volatile("s_waitcnt vmcnt(6)" ::: "memory");
    else if constexpr (N == 4) asm volatile("s_waitcnt vmcnt(4)" ::: "memory");
    else if constexpr (N == 2) asm volatile("s_waitcnt vmcnt(2)" ::: "memory");
    else                       asm volatile("s_waitcnt vmcnt(0)" ::: "memory");
    __builtin_amdgcn_sched_barrier(0);   // rule #18: keep MFMAs below the wait
}

__device__ __forceinline__ void lgkm0_barrier() {
    asm volatile("s_waitcnt lgkmcnt(0)" ::: "memory");  // publish my LDS writes
    __builtin_amdgcn_s_barrier();                        // raw: vmcnt NOT drained
}

__device__ __forceinline__ void issue_pro(const _Float16* bp, f16x8 (&b0s)[5], f16x8 (&b1s)[5]) {
    #pragma unroll
    for (int i = 0; i < 4; ++i)
        issue_b2(bp + i * 8192, b0s[i], b1s[i]);
}

// ---------------- pipelined GEMM (asm B-queue, 4 ks deep) ----------------
// Requires issue_pro(bp, ...) called earlier (slots 0..3 in flight).
template<int NKS>
__device__ __forceinline__ void gemm_pipe(
    f32x4 (&acc)[4][2], const _Float16* bp, const _Float16* ap,
    f16x8 (&b0s)[5], f16x8 (&b1s)[5])
{
    #pragma unroll
    for (int ks = 0; ks < NKS; ++ks) {
        f16x8 a0 = *(const f16x8*)(ap + ks * 32);
        f16x8 a1 = *(const f16x8*)(ap + 16 * ROWS + ks * 32);
        f16x8 a2 = *(const f16x8*)(ap + 32 * ROWS + ks * 32);
        f16x8 a3 = *(const f16x8*)(ap + 48 * ROWS + ks * 32);
        if (ks + 4 < NKS)
            issue_b2(bp + (ks + 4) * 8192, b0s[(ks + 4) % 5], b1s[(ks + 4) % 5]);
        // in flight: pairs ks .. min(ks+4, NKS-1); wait until pair ks done
        const int rem = NKS - 1 - ks;
        if (rem >= 4)      wait_vm<8>();
        else if (rem == 3) wait_vm<6>();
        else if (rem == 2) wait_vm<4>();
        else if (rem == 1) wait_vm<2>();
        else               wait_vm<0>();
        __builtin_amdgcn_s_setprio(1);
        acc[0][0] = __builtin_amdgcn_mfma_f32_16x16x32_f16(a0, b0s[ks % 5], acc[0][0], 0, 0, 0);
        acc[0][1] = __builtin_amdgcn_mfma_f32_16x16x32_f16(a0, b1s[ks % 5], acc[0][1], 0, 0, 0);
        acc[1][0] = __builtin_amdgcn_mfma_f32_16x16x32_f16(a1, b0s[ks % 5], acc[1][0], 0, 0, 0);
        acc[1][1] = __builtin_amdgcn_mfma_f32_16x16x32_f16(a1, b1s[ks % 5], acc[1][1], 0, 0, 0);
        acc[2][0] = __builtin_amdgcn_mfma_f32_16x16x32_f16(a2, b0s[ks % 5], acc[2][0], 0, 0, 0);
        acc[2][1] = __builtin_amdgcn_mfma_f32_16x16x32_f16(a2, b1s[ks % 5], acc[2][1], 0, 0, 0);
        acc[3][0] = __builtin_amdgcn_mfma_f32_16x16x32_f16(a3, b0s[ks % 5], acc[3][0], 0, 0, 0);
        acc[3][1] = __builtin_amdgcn_mfma_f32_16x16x32_f16(a3, b1s[ks % 5], acc[3][1], 0, 0, 0);
        __builtin_amdgcn_s_setprio(0);
    }
}

// ---------------- main fused kernel ----------------
template<bool PREPPED>
__global__ __launch_bounds__(512, 4) void iph_main(
    const float* __restrict__ feat,     // [128][256][2048]
    const float* __restrict__ coords,   // [128][2048][2]
    const float* __restrict__ params,   // [128][263169]
    const _Float16* __restrict__ wsw,   // fragment-ordered f16 weights
    const float* __restrict__ peg,      // [2][128]
    float* __restrict__ out)            // [128][1][2048]
{
    __shared__ _Float16 X[PT * ROWS];   // 68608 B
    __shared__ float    partial[8][PT]; // 2 KB -> 70.7 KB, 2 blocks/CU

    const int bid  = blockIdx.x;
    const int inst = (bid & 7) | ((bid >> 8) << 3);
    const int tile = (bid >> 3) & 31;
    const int p0   = tile * PT;
    const int tid  = threadIdx.x;
    const int lane = tid & 63;
    const int wave = tid >> 6;
    const int l15  = lane & 15;
    const int hi   = lane >> 4;
    const float* __restrict__ P = params + (size_t)inst * NPARAM;
    const _Float16* __restrict__ WI = wsw + (size_t)inst * WS_PER_INST;

    const _Float16* bp0 = WI + PI_L0 + ((wave * 2) * 64 + lane) * 8;
    const _Float16* bp1 = WI + PI_L1 + ((wave * 2) * 64 + lane) * 8;
    const _Float16* bp2 = WI + PI_L2 + ((wave * 2) * 64 + lane) * 8;
    const _Float16* ap  = &X[l15 * ROWS + hi * 8];

    f16x8 s0[5], s1[5], t0[5], t1[5], u0[5], u1[5];

    // ---- L0 B-prologue at kernel top: flies during PE + staging
    if (PREPPED) issue_pro(bp0, s0, s1);

    // ---- positional encoding -> X[pt][0..255], b128 writes
    {
        const int pt   = tid >> 3;     // 64 pts
        const int part = tid & 7;      // 16 freqs each
        const float2 cc = *(const float2*)&coords[((size_t)inst * NPTS + p0 + pt) * 2];
        const float a = 2.f * cc.x - 1.f;
        const float b = 2.f * cc.y - 1.f;
        float sv[16], cv[16];
        #pragma unroll
        for (int j = 0; j < 16; ++j) {
            const int f = part * 16 + j;
            float locr = a * peg[f] + b * peg[128 + f];
            locr -= floorf(locr);                        // period-1 reduction
            sv[j] = __builtin_amdgcn_sinf(locr);         // sin(2*pi*x)
            cv[j] = __builtin_amdgcn_cosf(locr);
        }
        pack8 q0, q1, c0, c1;
        #pragma unroll
        for (int q = 0; q < 4; ++q) {
            q0.h[q] = __builtin_amdgcn_cvt_pkrtz(sv[2*q],     sv[2*q + 1]);
            q1.h[q] = __builtin_amdgcn_cvt_pkrtz(sv[8 + 2*q], sv[9 + 2*q]);
            c0.h[q] = __builtin_amdgcn_cvt_pkrtz(cv[2*q],     cv[2*q + 1]);
            c1.h[q] = __builtin_amdgcn_cvt_pkrtz(cv[8 + 2*q], cv[9 + 2*q]);
        }
        _Float16* base = &X[pt * ROWS + part * 16];
        *(f16x8*)(base)           = q0.v;
        *(f16x8*)(base + 8)       = q1.v;
        *(f16x8*)(base + 128)     = c0.v;
        *(f16x8*)(base + 136)     = c1.v;
    }
    // ---- features -> X[pt][256..511], 8 dword loads -> one b128 write
    {
        const float* fbase = feat + (size_t)inst * CH * NPTS + p0 + lane;
        #pragma unroll
        for (int s = 0; s < 4; ++s) {
            const int c0i = s * 64 + wave * 8;
            float w8[8];
            #pragma unroll
            for (int j = 0; j < 8; ++j)
                w8[j] = fbase[(size_t)(c0i + j) * NPTS];
            pack8 pk;
            #pragma unroll
            for (int q = 0; q < 4; ++q)
                pk.h[q] = __builtin_amdgcn_cvt_pkrtz(w8[2*q], w8[2*q + 1]);
            *(f16x8*)&X[lane * ROWS + 256 + c0i] = pk.v;
        }
    }
    lgkm0_barrier();   // publish X; raw barrier keeps L0 prologue in flight

    auto write_epilogue = [&](f32x4 (&acc)[4][2], const float2 bb) {
        #pragma unroll
        for (int mt = 0; mt < 4; ++mt) {
            #pragma unroll
            for (int r = 0; r < 4; ++r) {
                // C/D layout (m89): col=lane&15, row=(lane>>4)*4+r
                const float v0 = fmaxf(acc[mt][0][r] + bb.x, 0.f);
                const float v1 = fmaxf(acc[mt][1][r] + bb.y, 0.f);
                const h16x2 e = __builtin_amdgcn_cvt_pkrtz(v0, v1);
                const int pt = mt * 16 + hi * 4 + r;
                *(h16x2*)&X[pt * ROWS + wave * 32 + 2 * l15] = e;
            }
        }
    };

    // fallback inner loop (no prep): r6 simple path
    auto gemm_simple = [&](f32x4 (&acc)[4][2], const float* pw, const int K) {
        for (int ks = 0; ks < (K >> 5); ++ks) {
            f16x8 bfrag[2];
            #pragma unroll
            for (int nt = 0; nt < 2; ++nt) {
                const int co = wave * 32 + 2 * l15 + nt;
                const float* wp = pw + (size_t)co * K + ks * 32 + hi * 8;
                float w8[8];
                __builtin_memcpy(w8, wp, 32);
                f16x8 bb;
                #pragma unroll
                for (int j = 0; j < 8; ++j) bb[j] = (_Float16)w8[j];
                bfrag[nt] = bb;
            }
            f16x8 afrag[4];
            #pragma unroll
            for (int mt = 0; mt < 4; ++mt)
                afrag[mt] = *(const f16x8*)&X[(mt * 16 + l15) * ROWS + ks * 32 + hi * 8];
            #pragma unroll
            for (int mt = 0; mt < 4; ++mt)
                #pragma unroll
                for (int nt = 0; nt < 2; ++nt)
                    acc[mt][nt] = __builtin_amdgcn_mfma_f32_16x16x32_f16(
                        afrag[mt], bfrag[nt], acc[mt][nt], 0, 0, 0);
        }
    };

    // ---- L0
    {
        f32x4 acc[4][2];
        #pragma unroll
        for (int mt = 0; mt < 4; ++mt)
            #pragma unroll
            for (int nt = 0; nt < 2; ++nt)
                acc[mt][nt] = (f32x4){0.f, 0.f, 0.f, 0.f};
        const float2 bb = *(const float2*)&P[BOFF0 + wave * 32 + 2 * l15];
        if (PREPPED) gemm_pipe<16>(acc, bp0, ap, s0, s1);
        else         gemm_simple(acc, P + WOFF0, 512);
        if (PREPPED) issue_pro(bp1, t0, t1);   // L1 prologue flies over epilogue
        __builtin_amdgcn_s_barrier();           // reads of X consumed by all
        write_epilogue(acc, bb);
        lgkm0_barrier();                        // publish L0 output
    }
    // ---- L1
    {
        f32x4 acc[4][2];
        #pragma unroll
        for (int mt = 0; mt < 4; ++mt)
            #pragma unroll
            for (int nt = 0; nt < 2; ++nt)
                acc[mt][nt] = (f32x4){0.f, 0.f, 0.f, 0.f};
        const float2 bb = *(const float2*)&P[BOFF1 + wave * 32 + 2 * l15];
        if (PREPPED) gemm_pipe<8>(acc, bp1, ap, t0, t1);
        else         gemm_simple(acc, P + WOFF1, 256);
        if (PREPPED) issue_pro(bp2, u0, u1);   // L2 prologue
        __builtin_amdgcn_s_barrier();
        write_epilogue(acc, bb);
        lgkm0_barrier();
    }
    // ---- L2 + L3 fused
    {
        f32x4 acc[4][2];
        #pragma unroll
        for (int mt = 0; mt < 4; ++mt)
            #pragma unroll
            for (int nt = 0; nt < 2; ++nt)
                acc[mt][nt] = (f32x4){0.f, 0.f, 0.f, 0.f};
        const float2 bb = *(const float2*)&P[BOFF2 + wave * 32 + 2 * l15];
        const float2 w3 = *(const float2*)&P[WOFF3 + wave * 32 + 2 * l15];
        if (PREPPED) gemm_pipe<8>(acc, bp2, ap, u0, u1);
        else         gemm_simple(acc, P + WOFF2, 256);
        #pragma unroll
        for (int mt = 0; mt < 4; ++mt) {
            #pragma unroll
            for (int r = 0; r < 4; ++r) {
                const float v0 = fmaxf(acc[mt][0][r] + bb.x, 0.f);
                const float v1 = fmaxf(acc[mt][1][r] + bb.y, 0.f);
                float s = v0 * w3.x + v1 * w3.y;
                s += __shfl_xor(s, 1);
                s += __shfl_xor(s, 2);
                s += __shfl_xor(s, 4);
                s += __shfl_xor(s, 8);
                if (l15 == 0)
                    partial[wave][mt * 16 + hi * 4 + r] = s;
            }
        }
        lgkm0_barrier();                        // publish partials
        if (tid < PT) {
            float s = P[BOFF3];
            #pragma unroll
            for (int w = 0; w < 8; ++w) s += partial[w][tid];
            out[(size_t)inst * NPTS + p0 + tid] = s;
        }
    }
}

extern "C" void kernel_launch(void* const* d_in, const int* in_sizes, int n_in,
                              void* d_out, int out_size, void* d_ws, size_t ws_size,
                              hipStream_t stream) {
    (void)in_sizes; (void)n_in; (void)out_size;
    const float* feat   = (const float*)d_in[0];
    const float* coords = (const float*)d_in[1];
    const float* params = (const float*)d_in[2];
    const float* peg    = (const float*)d_in[3];
    float* out = (float*)d_out;

    dim3 grid(NI * NTILES);   // 4096 blocks
    dim3 block(512);

    if (ws_size >= WS_BYTES) {
        _Float16* wsw = (_Float16*)d_ws;
        iph_prep<<<dim3(129, 128), dim3(256), 0, stream>>>(params, wsw);
        iph_main<true><<<grid, block, 0, stream>>>(feat, coords, params, wsw, peg, out);
    } else {
        iph_main<false><<<grid, block, 0, stream>>>(feat, coords, params,
                                                    (const _Float16*)d_ws, peg, out);
    }
}